// Round 2
// baseline (42.389 us; speedup 1.0000x reference)
//
#include <hip/hip_runtime.h>
#include <hip/hip_bf16.h>

// EMD loss: input (N,C,S)=(32,256,4096) fp32, target (N,S) int32.
// out = mean_{n,s}[ sum_c (cumsum_c(input) - [c>=target])^2 / S ]
//
// R1: float4 per thread -> 1024 B contiguous per wave per c-step (4x DRAM
// burst size vs R0's 256 B). 32768 threads as 512 blocks x 64 -> 2 waves/CU
// on all 256 CUs; unroll 16 keeps 16 float4 loads in flight per thread
// (32 KB/CU >> ~9 KB latency-BW product).

#define N_DIM 32
#define C_DIM 256
#define S_DIM 4096
#define S_SHIFT 12
#define G_PER_N (S_DIM / 4)      // 1024 float4 groups per n
#define G_MASK  (G_PER_N - 1)

__global__ __launch_bounds__(64) void emd_loss_kernel(
    const float4* __restrict__ in4, const int* __restrict__ tgt,
    float* __restrict__ out)
{
    const int g  = blockIdx.x * 64 + threadIdx.x;  // float4-group id in [0, 32768)
    const int n  = g >> 10;                        // g / G_PER_N
    const int s4 = g & G_MASK;

    const float4* p = in4 + (size_t)n * (C_DIM * (size_t)G_PER_N) + s4;

    const int j = (n << S_SHIFT) + (s4 << 2);      // target index, 16B-aligned
    const int4 T = *reinterpret_cast<const int4*>(tgt + j);

    float4 cum = make_float4(0.f, 0.f, 0.f, 0.f);
    float4 acc = make_float4(0.f, 0.f, 0.f, 0.f);

    #pragma unroll 16
    for (int c = 0; c < C_DIM; ++c) {
        const float4 v = p[(size_t)c * G_PER_N];
        cum.x += v.x; cum.y += v.y; cum.z += v.z; cum.w += v.w;
        const float d0 = cum.x - ((c >= T.x) ? 1.0f : 0.0f);
        const float d1 = cum.y - ((c >= T.y) ? 1.0f : 0.0f);
        const float d2 = cum.z - ((c >= T.z) ? 1.0f : 0.0f);
        const float d3 = cum.w - ((c >= T.w) ? 1.0f : 0.0f);
        acc.x = fmaf(d0, d0, acc.x);
        acc.y = fmaf(d1, d1, acc.y);
        acc.z = fmaf(d2, d2, acc.z);
        acc.w = fmaf(d3, d3, acc.w);
    }

    // /S (per-column norm) and /(N*S) (mean): 1/2^29, exact
    float a = (acc.x + acc.y + acc.z + acc.w)
            * (1.0f / ((float)S_DIM * (float)N_DIM * (float)S_DIM));

    // full-wave (block == 1 wave of 64) shuffle reduction
    #pragma unroll
    for (int off = 32; off > 0; off >>= 1)
        a += __shfl_down(a, off, 64);

    if (threadIdx.x == 0)
        atomicAdd(out, a);
}

extern "C" void kernel_launch(void* const* d_in, const int* in_sizes, int n_in,
                              void* d_out, int out_size, void* d_ws, size_t ws_size,
                              hipStream_t stream) {
    const float4* in4 = (const float4*)d_in[0];
    const int*    tgt = (const int*)d_in[1];
    float*        out = (float*)d_out;

    // atomic accumulation target must start at 0 every call (graph replays too)
    hipMemsetAsync(out, 0, sizeof(float), stream);

    const int groups = (N_DIM * S_DIM) / 4;        // 32768
    emd_loss_kernel<<<groups / 64, 64, 0, stream>>>(in4, tgt, out);
}